// Round 1
// baseline (11674.497 us; speedup 1.0000x reference)
//
#include <hip/hip_runtime.h>

#define NRES 64
#define GRID_CELLS (NRES * NRES * NRES)

__global__ void scatter_kernel(const float* __restrict__ x, int n, float sign,
                               float* __restrict__ grid) {
    int i = blockIdx.x * blockDim.x + threadIdx.x;
    if (i >= n) return;

    float px = x[3 * i + 0] * 64.0f;
    float py = x[3 * i + 1] * 64.0f;
    float pz = x[3 * i + 2] * 64.0f;

    int bx = (int)floorf(px - 0.5f);
    int by = (int)floorf(py - 0.5f);
    int bz = (int)floorf(pz - 0.5f);

    float fx = px - (float)bx;   // in [0.5, 1.5)
    float fy = py - (float)by;
    float fz = pz - (float)bz;

    float wx[3], wy[3], wz[3];
    wx[0] = 0.5f * (1.5f - fx) * (1.5f - fx);
    wx[1] = 0.75f - (fx - 1.0f) * (fx - 1.0f);
    wx[2] = 0.5f * (fx - 0.5f) * (fx - 0.5f);
    wy[0] = 0.5f * (1.5f - fy) * (1.5f - fy);
    wy[1] = 0.75f - (fy - 1.0f) * (fy - 1.0f);
    wy[2] = 0.5f * (fy - 0.5f) * (fy - 0.5f);
    wz[0] = 0.5f * (1.5f - fz) * (1.5f - fz);
    wz[1] = 0.75f - (fz - 1.0f) * (fz - 1.0f);
    wz[2] = 0.5f * (fz - 0.5f) * (fz - 0.5f);

    int baseIdx = (bx << 12) + (by << 6) + bz;

#pragma unroll
    for (int ii = 0; ii < 3; ++ii) {
#pragma unroll
        for (int jj = 0; jj < 3; ++jj) {
            float wij = wx[ii] * wy[jj] * sign;
            int idx = baseIdx + (ii << 12) + (jj << 6);
#pragma unroll
            for (int kk = 0; kk < 3; ++kk) {
                atomicAdd(&grid[idx + kk], wij * wz[kk]);
            }
        }
    }
}

__global__ void abs_reduce_kernel(const float* __restrict__ grid, float* __restrict__ out) {
    float s = 0.0f;
    for (int i = blockIdx.x * blockDim.x + threadIdx.x; i < GRID_CELLS;
         i += gridDim.x * blockDim.x) {
        s += fabsf(grid[i]);
    }
    // wave64 reduce
#pragma unroll
    for (int off = 32; off > 0; off >>= 1) {
        s += __shfl_down(s, off, 64);
    }
    __shared__ float ws[4];
    int lane = threadIdx.x & 63;
    int wid = threadIdx.x >> 6;
    if (lane == 0) ws[wid] = s;
    __syncthreads();
    if (threadIdx.x == 0) {
        float t = 0.0f;
        int nw = blockDim.x >> 6;
        for (int i = 0; i < nw; ++i) t += ws[i];
        atomicAdd(out, t);
    }
}

extern "C" void kernel_launch(void* const* d_in, const int* in_sizes, int n_in,
                              void* d_out, int out_size, void* d_ws, size_t ws_size,
                              hipStream_t stream) {
    const float* x     = (const float*)d_in[0];
    const float* x_ref = (const float*)d_in[1];
    float* out = (float*)d_out;
    float* grid = (float*)d_ws;

    int n = in_sizes[0] / 3;  // 4,000,000 particles

    hipMemsetAsync(grid, 0, GRID_CELLS * sizeof(float), stream);
    hipMemsetAsync(out, 0, sizeof(float), stream);

    int block = 256;
    int nblocks = (n + block - 1) / block;
    scatter_kernel<<<nblocks, block, 0, stream>>>(x, n, 1.0f, grid);
    scatter_kernel<<<nblocks, block, 0, stream>>>(x_ref, n, -1.0f, grid);

    abs_reduce_kernel<<<256, 256, 0, stream>>>(grid, out);
}

// Round 2
// 1267.234 us; speedup vs baseline: 9.2126x; 9.2126x over previous
//
#include <hip/hip_runtime.h>

#define NRES 64
#define GRID_CELLS (NRES * NRES * NRES)
#define SLABZ 4
#define NSLABS (NRES / SLABZ)   // 16
#define TPB 1024
#define MAXC 32

// LDS tile layout: idx = (x*64 + y)*4 + zl   (zl = z - slab*4), 64 KB
__global__ __launch_bounds__(TPB)
void slab_scatter_kernel(const float* __restrict__ x,
                         const float* __restrict__ xr,
                         int n, int C, float* __restrict__ partial) {
    __shared__ float tile[NRES * NRES * SLABZ];
    const int slab  = blockIdx.x / C;
    const int chunk = blockIdx.x - slab * C;
    const int z0 = slab * SLABZ;

    for (int i = threadIdx.x; i < NRES * NRES * SLABZ; i += TPB) tile[i] = 0.0f;
    __syncthreads();

    const int per = (n + C - 1) / C;
    const int p0 = chunk * per;
    const int p1 = min(n, p0 + per);

    for (int f = 0; f < 2; ++f) {
        const float* __restrict__ p = f ? xr : x;
        const float sgn = f ? -1.0f : 1.0f;
        for (int i = p0 + (int)threadIdx.x; i < p1; i += TPB) {
            float zs = p[3 * i + 2] * 64.0f;
            int bz = (int)floorf(zs - 0.5f);
            int zlo = bz - z0;                 // touches slab cells zlo..zlo+2
            if (zlo > SLABZ - 1 || zlo + 2 < 0) continue;

            float xs = p[3 * i + 0] * 64.0f;
            float ys = p[3 * i + 1] * 64.0f;
            int bx = (int)floorf(xs - 0.5f);
            int by = (int)floorf(ys - 0.5f);
            float fx = xs - (float)bx, fy = ys - (float)by, fz = zs - (float)bz;

            float wx0 = 0.5f * (1.5f - fx) * (1.5f - fx);
            float wx1 = 0.75f - (fx - 1.0f) * (fx - 1.0f);
            float wx2 = 0.5f * (fx - 0.5f) * (fx - 0.5f);
            float wy0 = 0.5f * (1.5f - fy) * (1.5f - fy);
            float wy1 = 0.75f - (fy - 1.0f) * (fy - 1.0f);
            float wy2 = 0.5f * (fy - 0.5f) * (fy - 0.5f);
            float wzv[3];
            wzv[0] = 0.5f * (1.5f - fz) * (1.5f - fz);
            wzv[1] = 0.75f - (fz - 1.0f) * (fz - 1.0f);
            wzv[2] = 0.5f * (fz - 0.5f) * (fz - 0.5f);

            float wxy[9];
            wxy[0] = sgn * wx0 * wy0; wxy[1] = sgn * wx0 * wy1; wxy[2] = sgn * wx0 * wy2;
            wxy[3] = sgn * wx1 * wy0; wxy[4] = sgn * wx1 * wy1; wxy[5] = sgn * wx1 * wy2;
            wxy[6] = sgn * wx2 * wy0; wxy[7] = sgn * wx2 * wy1; wxy[8] = sgn * wx2 * wy2;

            int base = (bx * 64 + by) * 4;
#pragma unroll
            for (int k = 0; k < 3; ++k) {
                int zl = zlo + k;
                if (zl < 0 || zl >= SLABZ) continue;
                float wzk = wzv[k];
                int a = base + zl;
#pragma unroll
                for (int i2 = 0; i2 < 3; ++i2)
#pragma unroll
                    for (int j2 = 0; j2 < 3; ++j2)
                        atomicAdd(&tile[a + i2 * 256 + j2 * 4], wxy[i2 * 3 + j2] * wzk);
            }
        }
    }
    __syncthreads();

    // flush tile (plain stores) to this chunk's partial grid replica
    float* __restrict__ dst = partial + (size_t)chunk * GRID_CELLS;
    for (int t = threadIdx.x; t < NRES * NRES; t += TPB) {
        float4 v = *reinterpret_cast<const float4*>(&tile[t * 4]);
        *reinterpret_cast<float4*>(&dst[t * 64 + z0]) = v;   // cell = (x*64+y)*64 + z0
    }
}

__global__ void reduce_kernel(const float* __restrict__ partial, int C,
                              float* __restrict__ out) {
    int cell = blockIdx.x * blockDim.x + threadIdx.x;   // grid sized exactly
    float s = 0.0f;
    for (int c = 0; c < C; ++c) s += partial[(size_t)c * GRID_CELLS + cell];
    s = fabsf(s);
#pragma unroll
    for (int off = 32; off > 0; off >>= 1) s += __shfl_down(s, off, 64);
    __shared__ float wsum[4];
    int lane = threadIdx.x & 63, wid = threadIdx.x >> 6;
    if (lane == 0) wsum[wid] = s;
    __syncthreads();
    if (threadIdx.x == 0) {
        atomicAdd(out, wsum[0] + wsum[1] + wsum[2] + wsum[3]);
    }
}

extern "C" void kernel_launch(void* const* d_in, const int* in_sizes, int n_in,
                              void* d_out, int out_size, void* d_ws, size_t ws_size,
                              hipStream_t stream) {
    const float* x  = (const float*)d_in[0];
    const float* xr = (const float*)d_in[1];
    float* out = (float*)d_out;
    float* partial = (float*)d_ws;

    int n = in_sizes[0] / 3;  // 4,000,000 particles

    int C = (int)(ws_size / ((size_t)GRID_CELLS * sizeof(float)));
    if (C > MAXC) C = MAXC;
    if (C < 1) C = 1;

    hipMemsetAsync(out, 0, sizeof(float), stream);
    slab_scatter_kernel<<<NSLABS * C, TPB, 0, stream>>>(x, xr, n, C, partial);
    reduce_kernel<<<GRID_CELLS / 256, 256, 0, stream>>>(partial, C, out);
}